// Round 1
// baseline (216.770 us; speedup 1.0000x reference)
//
#include <hip/hip_runtime.h>

// DVDNMixer: 8-fold PMF convolution (51 atoms -> 401) + C51 projection to 51 atoms.
//
// Math: support=linspace(-80,80,401), delta=0.4 => projection indices are integral:
//   out[0] = sum q[0..175]; out[j] = q[175+j] (1<=j<=49); out[50] = sum q[225..400]
//
// Parallelization: one 64-lane wave per (b,t) task. Conv in per-wave zero-padded
// LDS double buffer (branch-free edges; outputs beyond L_out compute to exact 0).
// Each lane produces R consecutive outputs from an (R+50)-float register window;
// p[j] broadcast via v_readlane (VALU pipe) from a per-lane register loaded from
// global. Odd R => window-read bank aliasing is 2-way (free).

#define N_ATOM  51
#define N_TASKS 32768            // BS*T = 128*256
#define BUFSZ   512
#define PAD     50
#define WPB     4                // waves per 256-thread block

template<int R>
__device__ __forceinline__ void conv_step(const float* __restrict__ gp,
                                          const float* bin, float* bout, int lane) {
  // per-lane copy of this agent's PMF; lanes >= 51 unused by readlane
  float pv = (lane < N_ATOM) ? gp[lane] : 0.f;
  const int o0 = lane * R;
  float W[R + PAD];
#pragma unroll
  for (int w = 0; w < R + PAD; ++w) W[w] = bin[o0 + w];
  float acc[R];
#pragma unroll
  for (int r = 0; r < R; ++r) acc[r] = 0.f;
#pragma unroll
  for (int j = 0; j < N_ATOM; ++j) {
    // wave-uniform broadcast of p[j] via SGPR (VALU pipe, no LDS traffic)
    float pj = __builtin_bit_cast(float,
        __builtin_amdgcn_readlane(__builtin_bit_cast(int, pv), j));
#pragma unroll
    for (int r = 0; r < R; ++r)
      acc[r] = fmaf(pj, W[r - j + PAD], acc[r]);
  }
#pragma unroll
  for (int r = 0; r < R; ++r) bout[PAD + o0 + r] = acc[r];
}

__global__ __launch_bounds__(256, 4)
void dvdn_mixer_kernel(const float* __restrict__ in, float* __restrict__ out) {
  __shared__ float buf[WPB][2][BUFSZ];
  const int lane = threadIdx.x & 63;
  const int wave = threadIdx.x >> 6;
  const int task = blockIdx.x * WPB + wave;

  const float* gp = in + (size_t)task * (8 * N_ATOM);
  float* b0 = buf[wave][0];
  float* b1 = buf[wave][1];

  // zero both buffers (pads stay zero forever; dirty regions are always
  // overwritten by the next step that writes that buffer)
#pragma unroll
  for (int i = lane; i < BUFSZ; i += 64) { b0[i] = 0.f; b1[i] = 0.f; }
  // stage agent 0 as the initial distribution
  if (lane < N_ATOM) b0[PAD + lane] = gp[lane];
  __syncthreads();

  // L_out per step: 101,151,201,251,301,351,401 ; covered = 64*R
  conv_step<3>(gp + 1 * N_ATOM, b0, b1, lane); __syncthreads();
  conv_step<3>(gp + 2 * N_ATOM, b1, b0, lane); __syncthreads();
  conv_step<5>(gp + 3 * N_ATOM, b0, b1, lane); __syncthreads();
  conv_step<5>(gp + 4 * N_ATOM, b1, b0, lane); __syncthreads();
  conv_step<5>(gp + 5 * N_ATOM, b0, b1, lane); __syncthreads();
  conv_step<7>(gp + 6 * N_ATOM, b1, b0, lane); __syncthreads();
  conv_step<7>(gp + 7 * N_ATOM, b0, b1, lane); __syncthreads();

  // final q[0..400] lives at b1[PAD..PAD+400]
  const float* q = b1 + PAD;

  // tail sums (atom 0 and atom 50), wave-parallel then butterfly reduce
  float s0 = 0.f, s1 = 0.f;
  for (int k = lane; k < 176; k += 64)       s0 += q[k];
  for (int k = 225 + lane; k < 401; k += 64) s1 += q[k];
#pragma unroll
  for (int d = 1; d < 64; d <<= 1) {
    s0 += __shfl_xor(s0, d, 64);
    s1 += __shfl_xor(s1, d, 64);
  }

  float* o = out + (size_t)task * N_ATOM;
  if (lane == 0) { o[0] = s0; o[50] = s1; }
  else if (lane < 50) o[lane] = q[175 + lane];
}

extern "C" void kernel_launch(void* const* d_in, const int* in_sizes, int n_in,
                              void* d_out, int out_size, void* d_ws, size_t ws_size,
                              hipStream_t stream) {
  const float* agent_qs = (const float*)d_in[0];  // [128,256,8,51] f32
  // d_in[1] (states) is unused by the reference computation
  float* out = (float*)d_out;                     // [128,256,51] f32
  dvdn_mixer_kernel<<<N_TASKS / WPB, 256, 0, stream>>>(agent_qs, out);
}